// Round 6
// baseline (984.489 us; speedup 1.0000x reference)
//
#include <hip/hip_runtime.h>
#include <math.h>

#define N_NODES 50000
#define N_EDGES 1600000
#define MAXROW  128

__device__ __forceinline__ float lrelu02(float x) { return x > 0.f ? x : 0.2f * x; }
__device__ __forceinline__ float elu1(float x)    { return x > 0.f ? x : __expf(x) - 1.f; }

// bf16 helpers (RNE pack)
__device__ __forceinline__ unsigned short f2bf(float f) {
    unsigned int u = __float_as_uint(f);
    return (unsigned short)((u + 0x7fffu + ((u >> 16) & 1u)) >> 16);
}
__device__ __forceinline__ float bf2f(unsigned short s) {
    return __uint_as_float((unsigned int)s << 16);
}
__device__ __forceinline__ float2 bfp2(unsigned int u) {
    float2 r;
    r.x = __uint_as_float(u << 16);
    r.y = __uint_as_float(u & 0xffff0000u);
    return r;
}

// ---------------- GEMM (layers 1/2, FOUT=64): h_bf = bf16(x @ W) ----------------
template<int FIN>
__global__ void gemm_kernel(const float* __restrict__ x, const float* __restrict__ W,
                            unsigned short* __restrict__ h, int FOUT) {
    __shared__ float Wl[FIN][64];
    const int tx = threadIdx.x, ty = threadIdx.y;
    for (int i = ty * 64 + tx; i < FIN * 64; i += 256) {
        int k = i >> 6, f = i & 63;
        Wl[k][f] = (f < FOUT) ? W[(size_t)k * FOUT + f] : 0.f;
    }
    __syncthreads();
    const int n0 = blockIdx.x * 32 + ty * 8;
    float acc[8] = {0.f, 0.f, 0.f, 0.f, 0.f, 0.f, 0.f, 0.f};
    if (n0 + 8 <= N_NODES) {
        for (int k = 0; k < FIN; k += 4) {
            float4 xv[8];
#pragma unroll
            for (int i = 0; i < 8; ++i)
                xv[i] = *(const float4*)(x + (size_t)(n0 + i) * FIN + k);
#pragma unroll
            for (int kk = 0; kk < 4; ++kk) {
                float w = Wl[k + kk][tx];
#pragma unroll
                for (int i = 0; i < 8; ++i) {
                    float xs = (kk == 0) ? xv[i].x : (kk == 1) ? xv[i].y : (kk == 2) ? xv[i].z : xv[i].w;
                    acc[i] = fmaf(xs, w, acc[i]);
                }
            }
        }
    } else {
        for (int i = 0; i < 8; ++i) {
            if (n0 + i >= N_NODES) break;
            const float* xr = x + (size_t)(n0 + i) * FIN;
            float a = 0.f;
            for (int k = 0; k < FIN; ++k) a = fmaf(xr[k], Wl[k][tx], a);
            acc[i] = a;
        }
    }
    if (tx < FOUT) {
#pragma unroll
        for (int i = 0; i < 8; ++i)
            if (n0 + i < N_NODES) h[(size_t)(n0 + i) * FOUT + tx] = f2bf(acc[i]);
    }
}

// ---------------- L3 GEMM: h[n,240] = bf16(x[n,64] @ W[64,240]), fused al3 ----------------
__global__ void gemm240_kernel(const float* __restrict__ x, const float* __restrict__ W,
                               const float* __restrict__ a_s, const float* __restrict__ a_d,
                               unsigned short* __restrict__ h,
                               float* __restrict__ al_s, float* __restrict__ al_d) {
    __shared__ float Wl[64][240];           // 61440 B
    __shared__ unsigned short ot[32][240];  // 15360 B
    const int tx = threadIdx.x, ty = threadIdx.y;
    const int tid = ty * 64 + tx;
    {
        const float4* W4 = (const float4*)W;
        float4* Wl4 = (float4*)&Wl[0][0];
        for (int i = tid; i < 64 * 240 / 4; i += 256) Wl4[i] = W4[i];
    }
    __syncthreads();
    const int n0b = blockIdx.x * 32;
    const int n0 = n0b + ty * 8;
    float acc[4][8];
#pragma unroll
    for (int g = 0; g < 4; ++g)
#pragma unroll
        for (int i = 0; i < 8; ++i) acc[g][i] = 0.f;
    const int tx3 = (tx < 48) ? (192 + tx) : 0;
    if (n0 + 8 <= N_NODES) {
        for (int k = 0; k < 64; k += 4) {
            float4 xv[8];
#pragma unroll
            for (int i = 0; i < 8; ++i)
                xv[i] = *(const float4*)(x + (size_t)(n0 + i) * 64 + k);
#pragma unroll
            for (int kk = 0; kk < 4; ++kk) {
                float w0 = Wl[k + kk][tx];
                float w1 = Wl[k + kk][64 + tx];
                float w2 = Wl[k + kk][128 + tx];
                float w3 = Wl[k + kk][tx3];
#pragma unroll
                for (int i = 0; i < 8; ++i) {
                    float xs = (kk == 0) ? xv[i].x : (kk == 1) ? xv[i].y : (kk == 2) ? xv[i].z : xv[i].w;
                    acc[0][i] = fmaf(xs, w0, acc[0][i]);
                    acc[1][i] = fmaf(xs, w1, acc[1][i]);
                    acc[2][i] = fmaf(xs, w2, acc[2][i]);
                    acc[3][i] = fmaf(xs, w3, acc[3][i]);
                }
            }
        }
    } else {
        for (int i = 0; i < 8; ++i) {
            if (n0 + i >= N_NODES) break;
            const float* xr = x + (size_t)(n0 + i) * 64;
            for (int k = 0; k < 64; ++k) {
                float xs = xr[k];
                acc[0][i] = fmaf(xs, Wl[k][tx], acc[0][i]);
                acc[1][i] = fmaf(xs, Wl[k][64 + tx], acc[1][i]);
                acc[2][i] = fmaf(xs, Wl[k][128 + tx], acc[2][i]);
                acc[3][i] = fmaf(xs, Wl[k][tx3], acc[3][i]);
            }
        }
    }
#pragma unroll
    for (int i = 0; i < 8; ++i) {
        ot[ty * 8 + i][tx] = f2bf(acc[0][i]);
        ot[ty * 8 + i][64 + tx] = f2bf(acc[1][i]);
        ot[ty * 8 + i][128 + tx] = f2bf(acc[2][i]);
        if (tx < 48) ot[ty * 8 + i][192 + tx] = f2bf(acc[3][i]);
    }
    __syncthreads();
    int vrows = N_NODES - n0b; if (vrows > 32) vrows = 32;
    {
        const unsigned int* po = (const unsigned int*)&ot[0][0];
        unsigned int* ph = (unsigned int*)(h + (size_t)n0b * 240);
        int limit = vrows * 120;
        for (int i = tid; i < limit; i += 256) ph[i] = po[i];
    }
    if (tid < 192) {
        int node = tid / 6, hd = tid % 6;
        if (node < vrows) {
            const unsigned short* r = &ot[node][hd * 40];
            const float* as = a_s + hd * 40;
            const float* ad = a_d + hd * 40;
            float s1 = 0.f, s2 = 0.f;
            for (int c = 0; c < 40; c += 2) {
                unsigned int q = *(const unsigned int*)(r + c);
                float2 p = bfp2(q);
                s1 = fmaf(p.x, as[c], s1);     s2 = fmaf(p.x, ad[c], s2);
                s1 = fmaf(p.y, as[c + 1], s1); s2 = fmaf(p.y, ad[c + 1], s2);
            }
            al_s[(n0b + node) * 6 + hd] = s1;
            al_d[(n0b + node) * 6 + hd] = s2;
        }
    }
}

// ---------------- per-(node,head) attention logits (layers 1/2) ----------------
__global__ void al_kernel(const unsigned short* __restrict__ h, const float* __restrict__ a_s,
                          const float* __restrict__ a_d, float* __restrict__ al_s,
                          float* __restrict__ al_d, int H, int C) {
    int i = blockIdx.x * blockDim.x + threadIdx.x;   // n*H + head
    if (i >= N_NODES * H) return;
    int n = i / H, hd = i % H;
    const unsigned short* hr = h + (size_t)n * H * C + hd * C;
    const float* as = a_s + hd * C;
    const float* ad = a_d + hd * C;
    float s1 = 0.f, s2 = 0.f;
    for (int c = 0; c < C; c += 8) {
        uint4 q = *(const uint4*)(hr + c);
        float2 p0 = bfp2(q.x), p1 = bfp2(q.y), p2 = bfp2(q.z), p3 = bfp2(q.w);
        s1 = fmaf(p0.x, as[c], s1);     s2 = fmaf(p0.x, ad[c], s2);
        s1 = fmaf(p0.y, as[c + 1], s1); s2 = fmaf(p0.y, ad[c + 1], s2);
        s1 = fmaf(p1.x, as[c + 2], s1); s2 = fmaf(p1.x, ad[c + 2], s2);
        s1 = fmaf(p1.y, as[c + 3], s1); s2 = fmaf(p1.y, ad[c + 3], s2);
        s1 = fmaf(p2.x, as[c + 4], s1); s2 = fmaf(p2.x, ad[c + 4], s2);
        s1 = fmaf(p2.y, as[c + 5], s1); s2 = fmaf(p2.y, ad[c + 5], s2);
        s1 = fmaf(p3.x, as[c + 6], s1); s2 = fmaf(p3.x, ad[c + 6], s2);
        s1 = fmaf(p3.y, as[c + 7], s1); s2 = fmaf(p3.y, ad[c + 7], s2);
    }
    al_s[i] = s1; al_d[i] = s2;
}

// ---------------- CSR build ----------------
__global__ void deg_kernel(const int* __restrict__ ei, int* __restrict__ deg) {
    int e = blockIdx.x * 256 + threadIdx.x;
    if (e >= N_EDGES) return;
    atomicAdd(&deg[ei[N_EDGES + e]], 1);
}

__global__ void scan_kernel(int* __restrict__ deg, int* __restrict__ rowptr) {
    __shared__ int sums[1024];
    int t = threadIdx.x;
    const int PER = (N_NODES + 1023) / 1024;  // 49
    int base = t * PER;
    int s = 0;
    for (int i = 0; i < PER; ++i) { int idx = base + i; if (idx < N_NODES) s += deg[idx]; }
    sums[t] = s;
    __syncthreads();
    for (int off = 1; off < 1024; off <<= 1) {
        int v = sums[t];
        int add = (t >= off) ? sums[t - off] : 0;
        __syncthreads();
        sums[t] = v + add;
        __syncthreads();
    }
    if (t == 0) rowptr[N_NODES] = sums[1023];
    int run = (t == 0) ? 0 : sums[t - 1];
    for (int i = 0; i < PER; ++i) {
        int idx = base + i;
        if (idx < N_NODES) {
            int d = deg[idx];
            rowptr[idx] = run;
            deg[idx] = run;       // cursor starts at row begin
            run += d;
        }
    }
}

__global__ void scatter_kernel(const int* __restrict__ ei, int* __restrict__ cursor,
                               unsigned short* __restrict__ csr_src) {
    int e = blockIdx.x * 256 + threadIdx.x;
    if (e >= N_EDGES) return;
    int src = ei[e], dst = ei[N_EDGES + e];
    int pos = atomicAdd(&cursor[dst], 1);
    csr_src[pos] = (unsigned short)src;   // N_NODES < 65536
}

// ---------------- sort each CSR row ascending (monotone h sweep => L2 locality) ----------------
__global__ void sort_rows_kernel(const int* __restrict__ rowptr, unsigned short* __restrict__ csr) {
    __shared__ unsigned short buf[64][MAXROW];
    int node = blockIdx.x * 64 + threadIdx.x;
    if (node >= N_NODES) return;
    int beg = rowptr[node], end = rowptr[node + 1];
    int len = end - beg;
    if (len <= 1) return;
    if (len <= MAXROW) {
        unsigned short* r = buf[threadIdx.x];
        for (int i = 0; i < len; ++i) r[i] = csr[beg + i];
        for (int i = 1; i < len; ++i) {
            unsigned short key = r[i];
            int k = i - 1;
            while (k >= 0 && r[k] > key) { r[k + 1] = r[k]; --k; }
            r[k + 1] = key;
        }
        for (int i = 0; i < len; ++i) csr[beg + i] = r[i];
    } else {
        for (int i = beg + 1; i < end; ++i) {
            unsigned short key = csr[i];
            int k = i - 1;
            while (k >= beg && csr[k] > key) { csr[k + 1] = csr[k]; --k; }
            csr[k + 1] = key;
        }
    }
}

// ---------------- gather aggregation, one wave per node ----------------
// HC = 64 (H=4, C=16): lane = channel; fused bias + ELU epilogue. 8x unrolled.
__global__ void agg64_kernel(const int* __restrict__ rowptr, const unsigned short* __restrict__ csr_src,
                             const float* __restrict__ al_s, const float* __restrict__ al_d,
                             const unsigned short* __restrict__ hb, const float* __restrict__ b,
                             float* __restrict__ xn) {
    int node = blockIdx.x * 4 + (threadIdx.x >> 6);   // grid exact: N_NODES % 4 == 0
    int lane = threadIdx.x & 63;
    int hd = lane >> 4;                               // C = 16
    float ald = al_d[node * 4 + hd];
    int beg = rowptr[node], end = rowptr[node + 1];
    float w = __expf(lrelu02(al_s[node * 4 + hd] + ald));
    float denom = w;
    float acc = w * bf2f(hb[(size_t)node * 64 + lane]);
    int j = beg;
    for (; j + 8 <= end; j += 8) {
        int s[8];
        unsigned short q[8];
#pragma unroll
        for (int u = 0; u < 8; ++u) s[u] = csr_src[j + u];
#pragma unroll
        for (int u = 0; u < 8; ++u) q[u] = hb[(size_t)s[u] * 64 + lane];
        float wv[8];
#pragma unroll
        for (int u = 0; u < 8; ++u) wv[u] = __expf(lrelu02(al_s[s[u] * 4 + hd] + ald));
#pragma unroll
        for (int u = 0; u < 8; ++u) {
            denom += wv[u];
            acc = fmaf(wv[u], bf2f(q[u]), acc);
        }
    }
    for (; j < end; ++j) {
        int s0 = csr_src[j];
        float w0 = __expf(lrelu02(al_s[s0 * 4 + hd] + ald));
        denom += w0;
        acc = fmaf(w0, bf2f(hb[(size_t)s0 * 64 + lane]), acc);
    }
    xn[(size_t)node * 64 + lane] = elu1(acc / denom + b[lane]);
}

// HC = 240 (H=6, C=40): lane handles 4 channels; 8x unrolled; FUSED final epilogue.
__global__ void agg240_kernel(const int* __restrict__ rowptr, const unsigned short* __restrict__ csr_src,
                              const float* __restrict__ al_s, const float* __restrict__ al_d,
                              const unsigned short* __restrict__ hb, const float* __restrict__ b3,
                              float* __restrict__ y) {
    __shared__ float sh[4][240];
    int wv_id = threadIdx.x >> 6;
    int node = blockIdx.x * 4 + wv_id;                // grid exact: 12500 blocks
    int lane = threadIdx.x & 63;
    bool act = lane < 60;
    int c0 = act ? lane * 4 : 0;
    int hd = c0 / 40;
    float ald = al_d[node * 6 + hd];
    int beg = rowptr[node], end = rowptr[node + 1];
    float w = __expf(lrelu02(al_s[node * 6 + hd] + ald));
    float denom = w;
    float4 acc;
    {
        uint2 q = *(const uint2*)(hb + (size_t)node * 240 + c0);
        float2 ab = bfp2(q.x), cd = bfp2(q.y);
        acc.x = w * ab.x; acc.y = w * ab.y; acc.z = w * cd.x; acc.w = w * cd.y;
    }
    int j = beg;
    for (; j + 8 <= end; j += 8) {
        int s[8];
        uint2 q[8];
#pragma unroll
        for (int u = 0; u < 8; ++u) s[u] = csr_src[j + u];
#pragma unroll
        for (int u = 0; u < 8; ++u) q[u] = *(const uint2*)(hb + (size_t)s[u] * 240 + c0);
        float wvv[8];
#pragma unroll
        for (int u = 0; u < 8; ++u) wvv[u] = __expf(lrelu02(al_s[s[u] * 6 + hd] + ald));
#pragma unroll
        for (int u = 0; u < 8; ++u) {
            denom += wvv[u];
            float2 ab = bfp2(q[u].x), cd = bfp2(q[u].y);
            acc.x = fmaf(wvv[u], ab.x, acc.x); acc.y = fmaf(wvv[u], ab.y, acc.y);
            acc.z = fmaf(wvv[u], cd.x, acc.z); acc.w = fmaf(wvv[u], cd.y, acc.w);
        }
    }
    for (; j < end; ++j) {
        int s0 = csr_src[j];
        uint2 q0 = *(const uint2*)(hb + (size_t)s0 * 240 + c0);
        float w0 = __expf(lrelu02(al_s[s0 * 6 + hd] + ald));
        denom += w0;
        float2 ab = bfp2(q0.x), cd = bfp2(q0.y);
        acc.x = fmaf(w0, ab.x, acc.x); acc.y = fmaf(w0, ab.y, acc.y);
        acc.z = fmaf(w0, cd.x, acc.z); acc.w = fmaf(w0, cd.y, acc.w);
    }
    if (act) {
        float r = 1.f / denom;
        float* sp = &sh[wv_id][c0];
        sp[0] = acc.x * r; sp[1] = acc.y * r; sp[2] = acc.z * r; sp[3] = acc.w * r;
    }
    __syncthreads();
    float v;
    if (lane < 40) {
        const float* p = sh[wv_id];
        float s = 0.f;
#pragma unroll
        for (int hh = 0; hh < 6; ++hh) s += p[hh * 40 + lane];
        v = elu1(s * (1.f / 6.f) + b3[lane]);
    } else {
        v = -INFINITY;
    }
    float m = v;
#pragma unroll
    for (int o = 32; o > 0; o >>= 1) m = fmaxf(m, __shfl_xor(m, o));
    float ex = (lane < 40) ? __expf(v - m) : 0.f;
    float ssum = ex;
#pragma unroll
    for (int o = 32; o > 0; o >>= 1) ssum += __shfl_xor(ssum, o);
    if (lane < 40) y[(size_t)node * 40 + lane] = v - m - __logf(ssum);
}

extern "C" void kernel_launch(void* const* d_in, const int* in_sizes, int n_in,
                              void* d_out, int out_size, void* d_ws, size_t ws_size,
                              hipStream_t stream) {
    const float* x   = (const float*)d_in[0];
    const int*   ei  = (const int*)d_in[1];   // [2, E]
    const float* W1  = (const float*)d_in[2];
    const float* a1s = (const float*)d_in[3];
    const float* a1d = (const float*)d_in[4];
    const float* b1  = (const float*)d_in[5];
    const float* W2  = (const float*)d_in[6];
    const float* a2s = (const float*)d_in[7];
    const float* a2d = (const float*)d_in[8];
    const float* b2  = (const float*)d_in[9];
    const float* W3  = (const float*)d_in[10];
    const float* a3s = (const float*)d_in[11];
    const float* a3d = (const float*)d_in[12];
    const float* b3  = (const float*)d_in[13];
    float* y = (float*)d_out;

    float* ws      = (float*)d_ws;
    unsigned short* h_bf = (unsigned short*)ws;           // 12,000,000 ushort (= 6.0M floats)
    float* x_buf   = ws + 6000000;                        //  3,200,000
    float* al_s    = ws + 9200000;                        //    300,000
    float* al_d    = ws + 9500000;                        //    300,000
    int*   deg     = (int*)(ws + 9800000);                //     50,000 (becomes cursor)
    int*   rowptr  = (int*)(ws + 9850000);                //     50,001
    unsigned short* csr_src = (unsigned short*)(ws + 9900008); // 1.6M ushort
    // total: 10,700,008 floats = 42.8 MB

    // ---- CSR build + row sort (once; shared by all 3 layers) ----
    hipMemsetAsync(deg, 0, N_NODES * sizeof(int), stream);
    deg_kernel<<<(N_EDGES + 255) / 256, 256, 0, stream>>>(ei, deg);
    scan_kernel<<<1, 1024, 0, stream>>>(deg, rowptr);
    scatter_kernel<<<(N_EDGES + 255) / 256, 256, 0, stream>>>(ei, deg, csr_src);
    sort_rows_kernel<<<(N_NODES + 63) / 64, 64, 0, stream>>>(rowptr, csr_src);

    const int agg_grid = N_NODES / 4;              // 12500, exact
    const int gemm_gx = (N_NODES + 31) / 32;

    // ---- layer 1: 128 -> (4,16) concat ----
    {
        dim3 gblk(64, 4), ggrd(gemm_gx, 1);
        gemm_kernel<128><<<ggrd, gblk, 0, stream>>>(x, W1, h_bf, 64);
        al_kernel<<<(N_NODES * 4 + 255) / 256, 256, 0, stream>>>(h_bf, a1s, a1d, al_s, al_d, 4, 16);
        agg64_kernel<<<agg_grid, 256, 0, stream>>>(rowptr, csr_src, al_s, al_d, h_bf, b1, x_buf);
    }

    // ---- layer 2: 64 -> (4,16) concat ----
    {
        dim3 gblk(64, 4), ggrd(gemm_gx, 1);
        gemm_kernel<64><<<ggrd, gblk, 0, stream>>>(x_buf, W2, h_bf, 64);
        al_kernel<<<(N_NODES * 4 + 255) / 256, 256, 0, stream>>>(h_bf, a2s, a2d, al_s, al_d, 4, 16);
        agg64_kernel<<<agg_grid, 256, 0, stream>>>(rowptr, csr_src, al_s, al_d, h_bf, b2, x_buf);
    }

    // ---- layer 3: 64 -> (6,40) mean; gemm fused with al3, agg fused with final ----
    {
        dim3 gblk(64, 4), ggrd(gemm_gx, 1);
        gemm240_kernel<<<ggrd, gblk, 0, stream>>>(x_buf, W3, a3s, a3d, h_bf, al_s, al_d);
        agg240_kernel<<<agg_grid, 256, 0, stream>>>(rowptr, csr_src, al_s, al_d, h_bf, b3, y);
    }
}

// Round 7
// 758.284 us; speedup vs baseline: 1.2983x; 1.2983x over previous
//
#include <hip/hip_runtime.h>
#include <math.h>

#define N_NODES 50000
#define N_EDGES 1600000

__device__ __forceinline__ float lrelu02(float x) { return x > 0.f ? x : 0.2f * x; }
__device__ __forceinline__ float elu1(float x)    { return x > 0.f ? x : __expf(x) - 1.f; }

// bf16 helpers (RNE pack)
__device__ __forceinline__ unsigned short f2bf(float f) {
    unsigned int u = __float_as_uint(f);
    return (unsigned short)((u + 0x7fffu + ((u >> 16) & 1u)) >> 16);
}
__device__ __forceinline__ float bf2f(unsigned short s) {
    return __uint_as_float((unsigned int)s << 16);
}
__device__ __forceinline__ float2 bfp2(unsigned int u) {
    float2 r;
    r.x = __uint_as_float(u << 16);
    r.y = __uint_as_float(u & 0xffff0000u);
    return r;
}

// ------- GEMM layers 1/2 (FOUT=64) fused with attention logits -------
// block (64,4): 32 nodes; padded LDS tile for conflict-free al dots;
// coalesced uint h writeout.
template<int FIN>
__global__ void gemm_al_kernel(const float* __restrict__ x, const float* __restrict__ W,
                               const float* __restrict__ a_s, const float* __restrict__ a_d,
                               unsigned short* __restrict__ h,
                               float* __restrict__ al_s, float* __restrict__ al_d) {
    __shared__ float Wl[FIN][64];
    __shared__ unsigned short ot[32][66];   // +2 pad: LDS rows stride 33 dwords
    const int tx = threadIdx.x, ty = threadIdx.y;
    const int tid = ty * 64 + tx;
    for (int i = tid; i < FIN * 64; i += 256) {
        int k = i >> 6, f = i & 63;
        Wl[k][f] = W[(size_t)k * 64 + f];
    }
    __syncthreads();
    const int n0b = blockIdx.x * 32;
    const int n0 = n0b + ty * 8;
    float acc[8] = {0.f, 0.f, 0.f, 0.f, 0.f, 0.f, 0.f, 0.f};
    if (n0 + 8 <= N_NODES) {
        for (int k = 0; k < FIN; k += 4) {
            float4 xv[8];
#pragma unroll
            for (int i = 0; i < 8; ++i)
                xv[i] = *(const float4*)(x + (size_t)(n0 + i) * FIN + k);
#pragma unroll
            for (int kk = 0; kk < 4; ++kk) {
                float w = Wl[k + kk][tx];
#pragma unroll
                for (int i = 0; i < 8; ++i) {
                    float xs = (kk == 0) ? xv[i].x : (kk == 1) ? xv[i].y : (kk == 2) ? xv[i].z : xv[i].w;
                    acc[i] = fmaf(xs, w, acc[i]);
                }
            }
        }
    } else {
        for (int i = 0; i < 8; ++i) {
            if (n0 + i >= N_NODES) break;
            const float* xr = x + (size_t)(n0 + i) * FIN;
            float a = 0.f;
            for (int k = 0; k < FIN; ++k) a = fmaf(xr[k], Wl[k][tx], a);
            acc[i] = a;
        }
    }
#pragma unroll
    for (int i = 0; i < 8; ++i) ot[ty * 8 + i][tx] = f2bf(acc[i]);
    __syncthreads();
    int vrows = N_NODES - n0b; if (vrows > 32) vrows = 32;
    // coalesced h writeout: vrows * 32 uints
    {
        unsigned int* ph = (unsigned int*)(h + (size_t)n0b * 64);
        for (int i = tid; i < vrows * 32; i += 256) {
            int row = i >> 5, col = i & 31;
            ph[i] = *(const unsigned int*)&ot[row][col * 2];
        }
    }
    // fused al: tid<128 -> (node, head); 16-elem dot
    if (tid < 128) {
        int node = tid >> 2, hd = tid & 3;
        if (node < vrows) {
            const float* as = a_s + hd * 16;
            const float* ad = a_d + hd * 16;
            float s1 = 0.f, s2 = 0.f;
#pragma unroll
            for (int c = 0; c < 16; c += 2) {
                unsigned int q = *(const unsigned int*)&ot[node][hd * 16 + c];
                float2 p = bfp2(q);
                s1 = fmaf(p.x, as[c], s1);     s2 = fmaf(p.x, ad[c], s2);
                s1 = fmaf(p.y, as[c + 1], s1); s2 = fmaf(p.y, ad[c + 1], s2);
            }
            al_s[(n0b + node) * 4 + hd] = s1;
            al_d[(n0b + node) * 4 + hd] = s2;
        }
    }
}

// ------- L3 GEMM: h[n,240] = bf16(x[n,64] @ W[64,240]), fused al3 -------
__global__ void gemm240_kernel(const float* __restrict__ x, const float* __restrict__ W,
                               const float* __restrict__ a_s, const float* __restrict__ a_d,
                               unsigned short* __restrict__ h,
                               float* __restrict__ al_s, float* __restrict__ al_d) {
    __shared__ float Wl[64][240];           // 61440 B
    __shared__ unsigned short ot[32][240];  // 15360 B
    const int tx = threadIdx.x, ty = threadIdx.y;
    const int tid = ty * 64 + tx;
    {
        const float4* W4 = (const float4*)W;
        float4* Wl4 = (float4*)&Wl[0][0];
        for (int i = tid; i < 64 * 240 / 4; i += 256) Wl4[i] = W4[i];
    }
    __syncthreads();
    const int n0b = blockIdx.x * 32;
    const int n0 = n0b + ty * 8;
    float acc[4][8];
#pragma unroll
    for (int g = 0; g < 4; ++g)
#pragma unroll
        for (int i = 0; i < 8; ++i) acc[g][i] = 0.f;
    const int tx3 = (tx < 48) ? (192 + tx) : 0;
    if (n0 + 8 <= N_NODES) {
        for (int k = 0; k < 64; k += 4) {
            float4 xv[8];
#pragma unroll
            for (int i = 0; i < 8; ++i)
                xv[i] = *(const float4*)(x + (size_t)(n0 + i) * 64 + k);
#pragma unroll
            for (int kk = 0; kk < 4; ++kk) {
                float w0 = Wl[k + kk][tx];
                float w1 = Wl[k + kk][64 + tx];
                float w2 = Wl[k + kk][128 + tx];
                float w3 = Wl[k + kk][tx3];
#pragma unroll
                for (int i = 0; i < 8; ++i) {
                    float xs = (kk == 0) ? xv[i].x : (kk == 1) ? xv[i].y : (kk == 2) ? xv[i].z : xv[i].w;
                    acc[0][i] = fmaf(xs, w0, acc[0][i]);
                    acc[1][i] = fmaf(xs, w1, acc[1][i]);
                    acc[2][i] = fmaf(xs, w2, acc[2][i]);
                    acc[3][i] = fmaf(xs, w3, acc[3][i]);
                }
            }
        }
    } else {
        for (int i = 0; i < 8; ++i) {
            if (n0 + i >= N_NODES) break;
            const float* xr = x + (size_t)(n0 + i) * 64;
            for (int k = 0; k < 64; ++k) {
                float xs = xr[k];
                acc[0][i] = fmaf(xs, Wl[k][tx], acc[0][i]);
                acc[1][i] = fmaf(xs, Wl[k][64 + tx], acc[1][i]);
                acc[2][i] = fmaf(xs, Wl[k][128 + tx], acc[2][i]);
                acc[3][i] = fmaf(xs, Wl[k][tx3], acc[3][i]);
            }
        }
    }
#pragma unroll
    for (int i = 0; i < 8; ++i) {
        ot[ty * 8 + i][tx] = f2bf(acc[0][i]);
        ot[ty * 8 + i][64 + tx] = f2bf(acc[1][i]);
        ot[ty * 8 + i][128 + tx] = f2bf(acc[2][i]);
        if (tx < 48) ot[ty * 8 + i][192 + tx] = f2bf(acc[3][i]);
    }
    __syncthreads();
    int vrows = N_NODES - n0b; if (vrows > 32) vrows = 32;
    {
        const unsigned int* po = (const unsigned int*)&ot[0][0];
        unsigned int* ph = (unsigned int*)(h + (size_t)n0b * 240);
        int limit = vrows * 120;
        for (int i = tid; i < limit; i += 256) ph[i] = po[i];
    }
    if (tid < 192) {
        int node = tid / 6, hd = tid % 6;
        if (node < vrows) {
            const unsigned short* r = &ot[node][hd * 40];
            const float* as = a_s + hd * 40;
            const float* ad = a_d + hd * 40;
            float s1 = 0.f, s2 = 0.f;
            for (int c = 0; c < 40; c += 2) {
                unsigned int q = *(const unsigned int*)(r + c);
                float2 p = bfp2(q);
                s1 = fmaf(p.x, as[c], s1);     s2 = fmaf(p.x, ad[c], s2);
                s1 = fmaf(p.y, as[c + 1], s1); s2 = fmaf(p.y, ad[c + 1], s2);
            }
            al_s[(n0b + node) * 6 + hd] = s1;
            al_d[(n0b + node) * 6 + hd] = s2;
        }
    }
}

// ---------------- CSR build ----------------
__global__ void deg_kernel(const int* __restrict__ ei, int* __restrict__ deg) {
    int e = blockIdx.x * 256 + threadIdx.x;
    if (e >= N_EDGES) return;
    atomicAdd(&deg[ei[N_EDGES + e]], 1);
}

__global__ void scan_kernel(int* __restrict__ deg, int* __restrict__ rowptr) {
    __shared__ int sums[1024];
    int t = threadIdx.x;
    const int PER = (N_NODES + 1023) / 1024;  // 49
    int base = t * PER;
    int s = 0;
    for (int i = 0; i < PER; ++i) { int idx = base + i; if (idx < N_NODES) s += deg[idx]; }
    sums[t] = s;
    __syncthreads();
    for (int off = 1; off < 1024; off <<= 1) {
        int v = sums[t];
        int add = (t >= off) ? sums[t - off] : 0;
        __syncthreads();
        sums[t] = v + add;
        __syncthreads();
    }
    if (t == 0) rowptr[N_NODES] = sums[1023];
    int run = (t == 0) ? 0 : sums[t - 1];
    for (int i = 0; i < PER; ++i) {
        int idx = base + i;
        if (idx < N_NODES) {
            int d = deg[idx];
            rowptr[idx] = run;
            deg[idx] = run;       // cursor starts at row begin
            run += d;
        }
    }
}

__global__ void scatter_kernel(const int* __restrict__ ei, int* __restrict__ cursor,
                               unsigned short* __restrict__ csr_src) {
    int e = blockIdx.x * 256 + threadIdx.x;
    if (e >= N_EDGES) return;
    int src = ei[e], dst = ei[N_EDGES + e];
    int pos = atomicAdd(&cursor[dst], 1);
    csr_src[pos] = (unsigned short)src;   // N_NODES < 65536
}

// ------- agg layers 1/2 (HC=64): dual-edge half-wave gather -------
// lanes 0-31 take even edges, 32-63 odd edges; each lane = 2 channels (uint load);
// halves combined via shfl_xor(32). Fused bias+ELU epilogue.
__global__ void agg64_kernel(const int* __restrict__ rowptr, const unsigned short* __restrict__ csr_src,
                             const float* __restrict__ al_s, const float* __restrict__ al_d,
                             const unsigned short* __restrict__ hb, const float* __restrict__ b,
                             float* __restrict__ xn) {
    int node = blockIdx.x * 4 + (threadIdx.x >> 6);   // grid exact: N_NODES % 4 == 0
    int lane = threadIdx.x & 63;
    int half = lane >> 5;
    int hl = lane & 31;
    int c0 = hl * 2;
    int hd = hl >> 3;                                 // head = (2*hl)/16
    float ald = al_d[node * 4 + hd];
    int beg = rowptr[node], end = rowptr[node + 1];
    float denom = 0.f, a0 = 0.f, a1 = 0.f;
    if (half == 0) {   // self loop on half 0
        float w = __expf(lrelu02(al_s[node * 4 + hd] + ald));
        float2 p = bfp2(*(const unsigned int*)(hb + (size_t)node * 64 + c0));
        denom = w; a0 = w * p.x; a1 = w * p.y;
    }
    int j = beg + half;
    for (; j + 6 < end; j += 8) {   // 4 edges per half = 8 edges per wave
        int s0 = csr_src[j], s1 = csr_src[j + 2], s2 = csr_src[j + 4], s3 = csr_src[j + 6];
        unsigned int q0 = *(const unsigned int*)(hb + (size_t)s0 * 64 + c0);
        unsigned int q1 = *(const unsigned int*)(hb + (size_t)s1 * 64 + c0);
        unsigned int q2 = *(const unsigned int*)(hb + (size_t)s2 * 64 + c0);
        unsigned int q3 = *(const unsigned int*)(hb + (size_t)s3 * 64 + c0);
        float w0 = __expf(lrelu02(al_s[s0 * 4 + hd] + ald));
        float w1 = __expf(lrelu02(al_s[s1 * 4 + hd] + ald));
        float w2 = __expf(lrelu02(al_s[s2 * 4 + hd] + ald));
        float w3 = __expf(lrelu02(al_s[s3 * 4 + hd] + ald));
        denom += (w0 + w1) + (w2 + w3);
        float2 p;
        p = bfp2(q0); a0 = fmaf(w0, p.x, a0); a1 = fmaf(w0, p.y, a1);
        p = bfp2(q1); a0 = fmaf(w1, p.x, a0); a1 = fmaf(w1, p.y, a1);
        p = bfp2(q2); a0 = fmaf(w2, p.x, a0); a1 = fmaf(w2, p.y, a1);
        p = bfp2(q3); a0 = fmaf(w3, p.x, a0); a1 = fmaf(w3, p.y, a1);
    }
    for (; j < end; j += 2) {
        int s0 = csr_src[j];
        unsigned int q0 = *(const unsigned int*)(hb + (size_t)s0 * 64 + c0);
        float w0 = __expf(lrelu02(al_s[s0 * 4 + hd] + ald));
        denom += w0;
        float2 p = bfp2(q0);
        a0 = fmaf(w0, p.x, a0); a1 = fmaf(w0, p.y, a1);
    }
    denom += __shfl_xor(denom, 32);
    a0 += __shfl_xor(a0, 32);
    a1 += __shfl_xor(a1, 32);
    if (half == 0) {
        float2 o;
        o.x = elu1(a0 / denom + b[c0]);
        o.y = elu1(a1 / denom + b[c0 + 1]);
        *(float2*)(xn + (size_t)node * 64 + c0) = o;
    }
}

// ------- agg layer 3 (HC=240): lane = 4 channels; fused final epilogue -------
__global__ void agg240_kernel(const int* __restrict__ rowptr, const unsigned short* __restrict__ csr_src,
                              const float* __restrict__ al_s, const float* __restrict__ al_d,
                              const unsigned short* __restrict__ hb, const float* __restrict__ b3,
                              float* __restrict__ y) {
    __shared__ float sh[4][240];
    int wv_id = threadIdx.x >> 6;
    int node = blockIdx.x * 4 + wv_id;                // grid exact: 12500 blocks
    int lane = threadIdx.x & 63;
    bool act = lane < 60;
    int c0 = act ? lane * 4 : 0;
    int hd = c0 / 40;
    float ald = al_d[node * 6 + hd];
    int beg = rowptr[node], end = rowptr[node + 1];
    float w = __expf(lrelu02(al_s[node * 6 + hd] + ald));
    float denom = w;
    float4 acc;
    {
        uint2 q = *(const uint2*)(hb + (size_t)node * 240 + c0);
        float2 ab = bfp2(q.x), cd = bfp2(q.y);
        acc.x = w * ab.x; acc.y = w * ab.y; acc.z = w * cd.x; acc.w = w * cd.y;
    }
    int j = beg;
    for (; j + 8 <= end; j += 8) {
        int s[8];
        uint2 q[8];
#pragma unroll
        for (int u = 0; u < 8; ++u) s[u] = csr_src[j + u];
#pragma unroll
        for (int u = 0; u < 8; ++u) q[u] = *(const uint2*)(hb + (size_t)s[u] * 240 + c0);
        float wvv[8];
#pragma unroll
        for (int u = 0; u < 8; ++u) wvv[u] = __expf(lrelu02(al_s[s[u] * 6 + hd] + ald));
#pragma unroll
        for (int u = 0; u < 8; ++u) {
            denom += wvv[u];
            float2 ab = bfp2(q[u].x), cd = bfp2(q[u].y);
            acc.x = fmaf(wvv[u], ab.x, acc.x); acc.y = fmaf(wvv[u], ab.y, acc.y);
            acc.z = fmaf(wvv[u], cd.x, acc.z); acc.w = fmaf(wvv[u], cd.y, acc.w);
        }
    }
    for (; j < end; ++j) {
        int s0 = csr_src[j];
        uint2 q0 = *(const uint2*)(hb + (size_t)s0 * 240 + c0);
        float w0 = __expf(lrelu02(al_s[s0 * 6 + hd] + ald));
        denom += w0;
        float2 ab = bfp2(q0.x), cd = bfp2(q0.y);
        acc.x = fmaf(w0, ab.x, acc.x); acc.y = fmaf(w0, ab.y, acc.y);
        acc.z = fmaf(w0, cd.x, acc.z); acc.w = fmaf(w0, cd.y, acc.w);
    }
    if (act) {
        float r = 1.f / denom;
        float* sp = &sh[wv_id][c0];
        sp[0] = acc.x * r; sp[1] = acc.y * r; sp[2] = acc.z * r; sp[3] = acc.w * r;
    }
    __syncthreads();
    float v;
    if (lane < 40) {
        const float* p = sh[wv_id];
        float s = 0.f;
#pragma unroll
        for (int hh = 0; hh < 6; ++hh) s += p[hh * 40 + lane];
        v = elu1(s * (1.f / 6.f) + b3[lane]);
    } else {
        v = -INFINITY;
    }
    float m = v;
#pragma unroll
    for (int o = 32; o > 0; o >>= 1) m = fmaxf(m, __shfl_xor(m, o));
    float ex = (lane < 40) ? __expf(v - m) : 0.f;
    float ssum = ex;
#pragma unroll
    for (int o = 32; o > 0; o >>= 1) ssum += __shfl_xor(ssum, o);
    if (lane < 40) y[(size_t)node * 40 + lane] = v - m - __logf(ssum);
}

extern "C" void kernel_launch(void* const* d_in, const int* in_sizes, int n_in,
                              void* d_out, int out_size, void* d_ws, size_t ws_size,
                              hipStream_t stream) {
    const float* x   = (const float*)d_in[0];
    const int*   ei  = (const int*)d_in[1];   // [2, E]
    const float* W1  = (const float*)d_in[2];
    const float* a1s = (const float*)d_in[3];
    const float* a1d = (const float*)d_in[4];
    const float* b1  = (const float*)d_in[5];
    const float* W2  = (const float*)d_in[6];
    const float* a2s = (const float*)d_in[7];
    const float* a2d = (const float*)d_in[8];
    const float* b2  = (const float*)d_in[9];
    const float* W3  = (const float*)d_in[10];
    const float* a3s = (const float*)d_in[11];
    const float* a3d = (const float*)d_in[12];
    const float* b3  = (const float*)d_in[13];
    float* y = (float*)d_out;

    float* ws      = (float*)d_ws;
    unsigned short* h_bf = (unsigned short*)ws;           // 12,000,000 ushort (= 6.0M floats)
    float* x_buf   = ws + 6000000;                        //  3,200,000
    float* al_s    = ws + 9200000;                        //    300,000
    float* al_d    = ws + 9500000;                        //    300,000
    int*   deg     = (int*)(ws + 9800000);                //     50,000 (becomes cursor)
    int*   rowptr  = (int*)(ws + 9850000);                //     50,001
    unsigned short* csr_src = (unsigned short*)(ws + 9900008); // 1.6M ushort
    // total: 10,700,008 floats = 42.8 MB

    // ---- CSR build (once; shared by all 3 layers) ----
    hipMemsetAsync(deg, 0, N_NODES * sizeof(int), stream);
    deg_kernel<<<(N_EDGES + 255) / 256, 256, 0, stream>>>(ei, deg);
    scan_kernel<<<1, 1024, 0, stream>>>(deg, rowptr);
    scatter_kernel<<<(N_EDGES + 255) / 256, 256, 0, stream>>>(ei, deg, csr_src);

    const int agg_grid = N_NODES / 4;              // 12500, exact
    const int gemm_gx = (N_NODES + 31) / 32;
    dim3 gblk(64, 4);

    // ---- layer 1: 128 -> (4,16) concat ----
    gemm_al_kernel<128><<<gemm_gx, gblk, 0, stream>>>(x, W1, a1s, a1d, h_bf, al_s, al_d);
    agg64_kernel<<<agg_grid, 256, 0, stream>>>(rowptr, csr_src, al_s, al_d, h_bf, b1, x_buf);

    // ---- layer 2: 64 -> (4,16) concat ----
    gemm_al_kernel<64><<<gemm_gx, gblk, 0, stream>>>(x_buf, W2, a2s, a2d, h_bf, al_s, al_d);
    agg64_kernel<<<agg_grid, 256, 0, stream>>>(rowptr, csr_src, al_s, al_d, h_bf, b2, x_buf);

    // ---- layer 3: 64 -> (6,40) mean ----
    gemm240_kernel<<<gemm_gx, gblk, 0, stream>>>(x_buf, W3, a3s, a3d, h_bf, al_s, al_d);
    agg240_kernel<<<agg_grid, 256, 0, stream>>>(rowptr, csr_src, al_s, al_d, h_bf, b3, y);
}